// Round 14
// baseline (367.512 us; speedup 1.0000x reference)
//
#include <hip/hip_runtime.h>
#include <hip/hip_bf16.h>
#include <stdint.h>

// ---------------------------------------------------------------------------
// TFEfficientFormerSelfAttention  (B=256, S=256, DIM=448, H=8, KD=32, EKD=128)
// Round 14: qkv GEMM moves from 2-phase (vmcnt(0)-drain per K-step) to the
// proj-proven 3-deep counted-vmcnt pipe3 (A dist-2 triple-buffer, B dist-1
// double-buffer, vmcnt(12) steady-state — loads stay in flight across
// barriers). pipe3 loses its sched_barrier(0) pins (memory clobber already
// fences; rule #18 applies to reg-consumers only) and gains T5 setprio(1)
// around each 16-MFMA cluster. attn (R13 cvt_pk version) untouched.
// Keeps: T1 XCD-chunked grid swizzle, T2 LDS XOR swizzle, swapped-MFMA QK
// epilogue, exp2 no-max softmax, bit-twiddle f2bf in GEMM epilogues.
// MFMA fragment layouts (verified m89/m91):
//   A: row=l&15, k=(l>>4)*8+j ; B: col=l&15, k=(l>>4)*8+j ;
//   D: col=l&15, row=(l>>4)*4+r.
// ---------------------------------------------------------------------------

typedef __attribute__((ext_vector_type(4))) float f32x4;
typedef __attribute__((ext_vector_type(8))) short short8;
typedef __attribute__((ext_vector_type(4))) unsigned short u16x4;
typedef __attribute__((ext_vector_type(2))) unsigned int u32x2;

#define DEVINL static __device__ __forceinline__

DEVINL unsigned short f2bf(float f) {
  unsigned u = __float_as_uint(f);
  return (unsigned short)((u + 0x7FFFu + ((u >> 16) & 1u)) >> 16);
}
DEVINL float bf2f(short s) {
  return __uint_as_float(((unsigned)(unsigned short)s) << 16);
}
DEVINL unsigned cvt_pk_bf16(float lo, float hi) {   // dest[15:0]=bf16(lo), [31:16]=bf16(hi)
  unsigned r;
  asm("v_cvt_pk_bf16_f32 %0, %1, %2" : "=v"(r) : "v"(lo), "v"(hi));
  return r;
}

DEVINL void gload_lds16(const void* g, void* l) {
  __builtin_amdgcn_global_load_lds((const __attribute__((address_space(1))) void*)g,
                                   (__attribute__((address_space(3))) void*)l,
                                   16, 0, 0);
}

#define SCALE 0.17677669529663687f
#define LOG2E 1.4426950408889634f

// ---------------- workspace layout (bytes) ----------------
#define WS_XB     ((size_t)0)            // 65536x448 bf16 (56MB), qkv only
#define WS_CTX    ((size_t)0)            // 65536x1024 bf16 (128MB), attn->proj
#define WS_WQT    ((size_t)134217728)    // 1536x448 bf16 (permuted, scaled)
#define WS_WPT    ((size_t)135593984)    // 512x1024 bf16 (rows 448..511 zero)
#define WS_QW     ((size_t)136642560)    // [2048][256][32] bf16 (scaled)
#define WS_KW     ((size_t)170196992)    // [2048][256][32] bf16
#define WS_VT     ((size_t)203751424)    // [2048][128][264] bf16
#define WS_QKVBP  ((size_t)342163456)    // 1536 f32 (permuted, scaled bias)

// column permutation: n' in [0,1536) -> n in original qkv order
DEVINL int qkv_perm(int np, float* sc) {
  *sc = 1.0f;
  if (np < 512) {
    const int h = np >> 6, c = np & 63;
    if (c < 32) *sc = SCALE * LOG2E;   // fold softmax scale + log2e into Q
    return h * 192 + c;
  }
  const int h = (np - 512) >> 7, e = (np - 512) & 127;
  return h * 192 + 64 + e;
}

// ---------------- prep kernels ----------------

__global__ void k_convert_x(const float* __restrict__ x, short* __restrict__ xb) {
  const size_t i = (size_t)blockIdx.x * blockDim.x + threadIdx.x;  // 8 elems each
  const f32x4* src = (const f32x4*)x + i * 2;
  f32x4 a = src[0], b = src[1];
  short8 o;
#pragma unroll
  for (int t = 0; t < 4; ++t) o[t] = (short)f2bf(a[t]);
#pragma unroll
  for (int t = 0; t < 4; ++t) o[4 + t] = (short)f2bf(b[t]);
  ((short8*)xb)[i] = o;
}

__global__ void k_prep_qkvw(const float* __restrict__ w, short* __restrict__ out) {
  const int idx = blockIdx.x * blockDim.x + threadIdx.x;  // [n'][k], 1536*448
  if (idx >= 1536 * 448) return;
  const int np = idx / 448, k = idx - np * 448;
  float sc;
  const int n = qkv_perm(np, &sc);
  out[idx] = (short)f2bf(w[(size_t)k * 1536 + n] * sc);
}

__global__ void k_prep_qkvb(const float* __restrict__ bsrc, float* __restrict__ bdst) {
  const int np = blockIdx.x * blockDim.x + threadIdx.x;
  if (np >= 1536) return;
  float sc;
  const int n = qkv_perm(np, &sc);
  bdst[np] = bsrc[n] * sc;
}

__global__ void k_transpose_bf16(const float* __restrict__ in, short* __restrict__ out,
                                 int K, int N, int total) {
  const int idx = blockIdx.x * blockDim.x + threadIdx.x;
  if (idx >= total) return;
  const int n = idx / K, k = idx - n * K;
  const float v = (n < N) ? in[(size_t)k * N + n] : 0.0f;
  out[idx] = (short)f2bf(v);
}

// ------- 128x128 GEMM mainloop: 3-deep counted-vmcnt pipeline (both GEMMs) -------
// A: 3 buffers (distance-2 prefetch covers HBM/L3-cold loads); B: 2 buffers.
// Issue order per step {B(k+1), A(k+2)} => steady s_waitcnt vmcnt(12) retires
// exactly {A(k),B(k)} (in-order retirement); 12 loads stay in flight across
// raw s_barriers. T2 XOR-swizzled LDS. T5 setprio around MFMA clusters.

template <int KSTEPS, int LDA, int LDB, bool SWAP>
DEVINL void gemm128_pipe3(const short* __restrict__ A, const short* __restrict__ B,
                          short* Asm /*3*8192*/, short* Bsm /*2*8192*/,
                          int m0, int n0, int tid, f32x4 acc[4][4]) {
  const int lane = tid & 63, wave = tid >> 6;
  const int l15 = lane & 15, g = lane >> 4;
  const int wm = wave >> 1, wn = wave & 1;
  const int r8 = lane >> 3;
  const int scol = (((lane & 7) ^ r8) << 3);
  const int wbase = wave * 32;

  const short* Ab = A + (size_t)(m0 + wbase + r8) * LDA + scol;
  const short* Bb = B + (size_t)(n0 + wbase + r8) * LDB + scol;

  auto stageA = [&](int k) {
    short* dst = Asm + (k % 3) * 8192 + wbase * 64;
    const short* src = Ab + (size_t)k * 64;
#pragma unroll
    for (int c = 0; c < 4; ++c) gload_lds16(src + (size_t)(c * 8) * LDA, dst + c * 512);
  };
  auto stageB = [&](int k) {
    short* dst = Bsm + (k % 2) * 8192 + wbase * 64;
    const short* src = Bb + (size_t)k * 64;
#pragma unroll
    for (int c = 0; c < 4; ++c) gload_lds16(src + (size_t)(c * 8) * LDB, dst + c * 512);
  };
  auto compute = [&](int k) {
    const short* Ac = Asm + (k % 3) * 8192;
    const short* Bc = Bsm + (k % 2) * 8192;
#pragma unroll
    for (int s = 0; s < 2; ++s) {
      const int rslot = (((s * 4 + g) ^ (l15 & 7)) << 3);
      short8 a[4], b[4];
#pragma unroll
      for (int i = 0; i < 4; ++i)
        a[i] = *(const short8*)(Ac + (wm * 64 + i * 16 + l15) * 64 + rslot);
#pragma unroll
      for (int j = 0; j < 4; ++j)
        b[j] = *(const short8*)(Bc + (wn * 64 + j * 16 + l15) * 64 + rslot);
      __builtin_amdgcn_s_setprio(1);
#pragma unroll
      for (int i = 0; i < 4; ++i)
#pragma unroll
        for (int j = 0; j < 4; ++j)
          acc[i][j] = SWAP
              ? __builtin_amdgcn_mfma_f32_16x16x32_bf16(b[j], a[i], acc[i][j], 0, 0, 0)
              : __builtin_amdgcn_mfma_f32_16x16x32_bf16(a[i], b[j], acc[i][j], 0, 0, 0);
      __builtin_amdgcn_s_setprio(0);
    }
  };

  stageB(0); stageA(0); stageA(1);
  asm volatile("s_waitcnt vmcnt(4)" ::: "memory");
  __builtin_amdgcn_s_barrier();

#pragma unroll
  for (int ks = 0; ks < KSTEPS - 2; ++ks) {
    stageB(ks + 1);
    stageA(ks + 2);
    asm volatile("s_waitcnt vmcnt(12)" ::: "memory");
    __builtin_amdgcn_s_barrier();
    compute(ks);
    __builtin_amdgcn_s_barrier();
  }
  stageB(KSTEPS - 1);
  asm volatile("s_waitcnt vmcnt(8)" ::: "memory");
  __builtin_amdgcn_s_barrier();
  compute(KSTEPS - 2);
  __builtin_amdgcn_s_barrier();
  asm volatile("s_waitcnt vmcnt(0)" ::: "memory");
  __builtin_amdgcn_s_barrier();
  compute(KSTEPS - 1);
}

// ---------------- QKV GEMM: Xb[65536][448] @ W'^T -> Q/K/Vt ----------------

union QkvSmem {
  struct { short a[3 * 8192]; short b[2 * 8192]; } ab;   // 80 KB pipe3 buffers
  short tile[128 * 136];                                  // V epilogue transpose
};

__global__ __launch_bounds__(256) void k_qkv_gemm(
    const short* __restrict__ Xb, const short* __restrict__ Wt,
    const float* __restrict__ qkvbp,
    short* __restrict__ Qw, short* __restrict__ Kw, short* __restrict__ Vt) {
  __shared__ __align__(16) QkvSmem sm;
  const int tid = threadIdx.x;
  const int l = (blockIdx.x & 7) * 768 + (blockIdx.x >> 3);
  const int mt = l / 12, by = l - mt * 12;
  const int m0 = mt * 128, n0 = by * 128;

  const int lane = tid & 63, wave = tid >> 6;
  const int l15 = lane & 15, g = lane >> 4;
  const int wm = wave >> 1, wn = wave & 1;
  const int b0 = m0 >> 8, s0 = m0 & 255;

  f32x4 acc[4][4];
#pragma unroll
  for (int i = 0; i < 4; ++i)
#pragma unroll
    for (int j = 0; j < 4; ++j) acc[i][j] = (f32x4){0.f, 0.f, 0.f, 0.f};

  if (by >= 4) {
    gemm128_pipe3<7, 448, 448, false>(Xb, Wt, sm.ab.a, sm.ab.b, m0, n0, tid, acc);
    __syncthreads();   // pipe3 ends barrier-less; ab dead, tile goes live
#pragma unroll
    for (int i = 0; i < 4; ++i) {
#pragma unroll
      for (int j = 0; j < 4; ++j) {
        const float bv = qkvbp[n0 + wn * 64 + j * 16 + l15];
        u16x4 pk;
#pragma unroll
        for (int r = 0; r < 4; ++r) pk[r] = f2bf(acc[i][j][r] + bv);
        *(u16x4*)&sm.tile[(wn * 64 + j * 16 + l15) * 136 + wm * 64 + i * 16 + g * 4] = pk;
      }
    }
    __syncthreads();
    const int bh = b0 * 8 + (by - 4);
#pragma unroll
    for (int p = 0; p < 8; ++p) {
      const int er = p * 16 + (tid >> 4);
      const int sc = (tid & 15) * 8;
      short8 v = *(const short8*)&sm.tile[er * 136 + sc];
      *(short8*)(Vt + (size_t)bh * 33792 + er * 264 + s0 + sc) = v;
    }
  } else {
    gemm128_pipe3<7, 448, 448, true>(Xb, Wt, sm.ab.a, sm.ab.b, m0, n0, tid, acc);
#pragma unroll
    for (int i = 0; i < 4; ++i) {
      const int s = s0 + wm * 64 + i * 16 + l15;
#pragma unroll
      for (int j = 0; j < 4; ++j) {
        const int nbase = n0 + wn * 64 + j * 16 + g * 4;
        const f32x4 bv4 = *(const f32x4*)(qkvbp + nbase);
        u16x4 pk;
#pragma unroll
        for (int r = 0; r < 4; ++r) pk[r] = f2bf(acc[i][j][r] + bv4[r]);
        const int c = nbase & 63;
        const int bh = b0 * 8 + (by << 1) + (nbase >> 6 & 1);
        short* dst = (c < 32) ? (Qw + ((size_t)bh * 256 + s) * 32 + c)
                              : (Kw + ((size_t)bh * 256 + s) * 32 + (c - 32));
        *(u16x4*)dst = pk;
      }
    }
  }
}

// ---------------- fused attention per (b,h) ----------------
// R13 version: swapped-score exp2 no-max, cvt_pk bf16 stores, read-only
// row-sum, 2 barriers/phase, issue-early loads.

__global__ __launch_bounds__(512, 4) void k_attn(
    const short* __restrict__ Qw, const short* __restrict__ Kw,
    const short* __restrict__ Vt, const float* __restrict__ attb, int n_off,
    short* __restrict__ CTX) {
  __shared__ short Ps[4][32 * 264];
  __shared__ float rinv[2][4][32];
  __shared__ float bias_sm[256];

  const int tid = threadIdx.x, lane = tid & 63, wave = tid >> 6;  // 8 waves
  const int l15 = lane & 15, g = lane >> 4;
  const int bh = blockIdx.x;
  const int b = bh >> 3, h = bh & 7;

  if (tid < 256) bias_sm[tid] = attb[h * n_off + tid] * LOG2E;  // exp2 domain
  __syncthreads();

  int offc[4];
#pragma unroll
  for (int r = 0; r < 4; ++r) {
    const int d = g * 4 + r - l15;
    offc[r] = (d < 0) ? -d : d;
  }

  const short* Qb = Qw + (size_t)bh * 8192;
  const short* Kb = Kw + (size_t)bh * 8192;
  const short* Vb = Vt + (size_t)bh * 33792;
  const int e = wave * 16 + l15;

  for (int ph = 0; ph < 2; ++ph) {
    const int Q0 = ph * 128;

    // ---- issue all phase loads up-front (independent 16B each) ----
    short8 aq[4][2];
#pragma unroll
    for (int u = 0; u < 4; ++u)
#pragma unroll
      for (int i = 0; i < 2; ++i)
        aq[u][i] = *(const short8*)(Qb + (Q0 + u * 32 + i * 16 + l15) * 32 + g * 8);
    short8 bkk[2];
#pragma unroll
    for (int fj = 0; fj < 2; ++fj)
      bkk[fj] = *(const short8*)(Kb + (wave * 32 + fj * 16 + l15) * 32 + g * 8);
    short8 bvv[8];
#pragma unroll
    for (int ks = 0; ks < 8; ++ks)
      bvv[ks] = *(const short8*)(Vb + e * 264 + ks * 32 + g * 8);

    // ---- scores (swapped): wave covers keys [wave*32, +32). D[k][q]. ----
#pragma unroll
    for (int fj = 0; fj < 2; ++fj) {
      const int kk0 = wave * 32 + fj * 16;
      const int kr = wave * 2 + fj;
#pragma unroll
      for (int u = 0; u < 4; ++u) {
#pragma unroll
        for (int i = 0; i < 2; ++i) {
          const int qr = ph * 8 + u * 2 + i;
          const int ab = ((qr > kr) ? qr - kr : kr - qr) << 4;
          f32x4 acc;
#pragma unroll
          for (int r = 0; r < 4; ++r) acc[r] = bias_sm[ab + offc[r]];
          acc = __builtin_amdgcn_mfma_f32_16x16x32_bf16(bkk[fj], aq[u][i], acc, 0, 0, 0);
          u32x2 pk;
          pk.x = cvt_pk_bf16(exp2f(acc[0]), exp2f(acc[1]));
          pk.y = cvt_pk_bf16(exp2f(acc[2]), exp2f(acc[3]));
          *(u32x2*)&Ps[u][(i * 16 + l15) * 264 + kk0 + g * 4] = pk;
        }
      }
    }
    __syncthreads();  // B1: all P written

    // ---- row-sum (read-only): 512 threads = 32 rows x 16 parts ----
    {
      const int r = tid >> 4, part = tid & 15;
#pragma unroll
      for (int u = 0; u < 4; ++u) {
        const short* rowp = &Ps[u][r * 264 + part * 16];
        short8 x0 = ((const short8*)rowp)[0];
        short8 x1 = ((const short8*)rowp)[1];
        float sum = 0.f;
#pragma unroll
        for (int t = 0; t < 8; ++t) sum += bf2f(x0[t]) + bf2f(x1[t]);
#pragma unroll
        for (int d = 1; d < 16; d <<= 1) sum += __shfl_xor(sum, d);
        if (part == 0) rinv[ph][u][r] = 1.0f / sum;
      }
    }
    // no barrier: rinv only read after B2 below

    // ---- PV direct (A=P rows q, B=V^T cols e from REGISTERS) ----
    f32x4 cacc[4][2];
#pragma unroll
    for (int u = 0; u < 4; ++u)
#pragma unroll
      for (int qt = 0; qt < 2; ++qt) cacc[u][qt] = (f32x4){0.f, 0.f, 0.f, 0.f};

#pragma unroll
    for (int ks = 0; ks < 8; ++ks) {
#pragma unroll
      for (int u = 0; u < 4; ++u)
#pragma unroll
        for (int qt = 0; qt < 2; ++qt) {
          const short8 ap = *(const short8*)&Ps[u][(qt * 16 + l15) * 264 + ks * 32 + g * 8];
          cacc[u][qt] = __builtin_amdgcn_mfma_f32_16x16x32_bf16(ap, bvv[ks], cacc[u][qt], 0, 0, 0);
        }
    }
    __syncthreads();  // B2: Ps consumed (free for next phase), rinv visible

    // ---- epilogue: apply rinv, store ctx (cvt_pk pairs) ----
#pragma unroll
    for (int u = 0; u < 4; ++u)
#pragma unroll
      for (int qt = 0; qt < 2; ++qt) {
        const int qb = qt * 16 + g * 4;
        const size_t base = ((size_t)b * 256 + Q0 + u * 32 + qb) * 1024 + h * 128 + wave * 16 + l15;
#pragma unroll
        for (int r = 0; r < 4; r += 2) {
          const unsigned pw = cvt_pk_bf16(cacc[u][qt][r] * rinv[ph][u][qb + r],
                                          cacc[u][qt][r + 1] * rinv[ph][u][qb + r + 1]);
          CTX[base + (size_t)r * 1024] = (short)(pw & 0xffffu);
          CTX[base + (size_t)(r + 1) * 1024] = (short)(pw >> 16);
        }
      }
  }
}

// ---------------- proj GEMM: CTX[65536][1024] @ WPT -> out f32 ----------------

__global__ __launch_bounds__(256) void k_proj_gemm(
    const short* __restrict__ CTX, const short* __restrict__ Wpt,
    const float* __restrict__ projb, float* __restrict__ out) {
  __shared__ __align__(16) short Asm[3 * 8192];
  __shared__ __align__(16) short Bsm[2 * 8192];
  const int tid = threadIdx.x;
  const int l = (blockIdx.x & 7) * 256 + (blockIdx.x >> 3);
  const int mt = l >> 2, nt = l & 3;
  const int m0 = mt * 128, n0 = nt * 128;
  f32x4 acc[4][4];
#pragma unroll
  for (int i = 0; i < 4; ++i)
#pragma unroll
    for (int j = 0; j < 4; ++j) acc[i][j] = (f32x4){0.f, 0.f, 0.f, 0.f};

  gemm128_pipe3<16, 1024, 1024, false>(CTX, Wpt, Asm, Bsm, m0, n0, tid, acc);

  const int lane = tid & 63, wave = tid >> 6;
  const int l15 = lane & 15, g = lane >> 4;
  const int wm = wave >> 1, wn = wave & 1;
#pragma unroll
  for (int i = 0; i < 4; ++i) {
    const int mb = m0 + wm * 64 + i * 16 + g * 4;
#pragma unroll
    for (int j = 0; j < 4; ++j) {
      const int n = n0 + wn * 64 + j * 16 + l15;
      if (n < 448) {
        const float bv = projb[n];
#pragma unroll
        for (int r = 0; r < 4; ++r)
          out[(size_t)(mb + r) * 448 + n] = acc[i][j][r] + bv;
      }
    }
  }
}

// ---------------- launch ----------------

extern "C" void kernel_launch(void* const* d_in, const int* in_sizes, int n_in,
                              void* d_out, int out_size, void* d_ws, size_t ws_size,
                              hipStream_t stream) {
  const float* X      = (const float*)d_in[0];
  const float* qkv_w  = (const float*)d_in[1];
  const float* qkv_b  = (const float*)d_in[2];
  const float* proj_w = (const float*)d_in[3];
  const float* proj_b = (const float*)d_in[4];
  const float* att_b  = (const float*)d_in[5];
  const int n_off = in_sizes[5] / 8;

  char* ws = (char*)d_ws;
  short* Xb    = (short*)(ws + WS_XB);
  short* CTX   = (short*)(ws + WS_CTX);
  short* WQT   = (short*)(ws + WS_WQT);
  short* WPT   = (short*)(ws + WS_WPT);
  short* Qw    = (short*)(ws + WS_QW);
  short* Kw    = (short*)(ws + WS_KW);
  short* Vt    = (short*)(ws + WS_VT);
  float* QKVBP = (float*)(ws + WS_QKVBP);

  k_convert_x<<<14336, 256, 0, stream>>>(X, Xb);
  k_prep_qkvw<<<(1536 * 448 + 255) / 256, 256, 0, stream>>>(qkv_w, WQT);
  k_prep_qkvb<<<6, 256, 0, stream>>>(qkv_b, QKVBP);
  k_transpose_bf16<<<(512 * 1024 + 255) / 256, 256, 0, stream>>>(proj_w, WPT, 1024, 448, 512 * 1024);

  k_qkv_gemm<<<6144, 256, 0, stream>>>(Xb, WQT, QKVBP, Qw, Kw, Vt);
  k_attn<<<2048, 512, 0, stream>>>(Qw, Kw, Vt, att_b, n_off, CTX);
  k_proj_gemm<<<2048, 256, 0, stream>>>(CTX, WPT, proj_b, (float*)d_out);
}

// Round 15
// 360.040 us; speedup vs baseline: 1.0208x; 1.0208x over previous
//
#include <hip/hip_runtime.h>
#include <hip/hip_bf16.h>
#include <stdint.h>

// ---------------------------------------------------------------------------
// TFEfficientFormerSelfAttention  (B=256, S=256, DIM=448, H=8, KD=32, EKD=128)
// Round 15: pipe3 restored to the R13-proven schedule (sched_barrier(0)
// order-pin after every counted-vmcnt barrier, NO setprio — R14's A/B showed
// removing the pin sinks issue-work into compute: proj 133->139, VALUBusy
// 25->9%). pipe3 now templated with SWAP and used by BOTH GEMMs (qkv keeps
// the R14 pipe3 transplant, which dropped it below proj).
// Keeps: R13 attn (swapped-score exp2 no-max, cvt_pk stores, read-only
// row-sum, 2 barriers/phase), T1 XCD-chunked grid swizzle, T2 LDS swizzle,
// swapped-MFMA QK epilogue, bit-twiddle f2bf.
// MFMA fragment layouts (verified m89/m91):
//   A: row=l&15, k=(l>>4)*8+j ; B: col=l&15, k=(l>>4)*8+j ;
//   D: col=l&15, row=(l>>4)*4+r.
// ---------------------------------------------------------------------------

typedef __attribute__((ext_vector_type(4))) float f32x4;
typedef __attribute__((ext_vector_type(8))) short short8;
typedef __attribute__((ext_vector_type(4))) unsigned short u16x4;
typedef __attribute__((ext_vector_type(2))) unsigned int u32x2;

#define DEVINL static __device__ __forceinline__

DEVINL unsigned short f2bf(float f) {
  unsigned u = __float_as_uint(f);
  return (unsigned short)((u + 0x7FFFu + ((u >> 16) & 1u)) >> 16);
}
DEVINL float bf2f(short s) {
  return __uint_as_float(((unsigned)(unsigned short)s) << 16);
}
DEVINL unsigned cvt_pk_bf16(float lo, float hi) {   // dest[15:0]=bf16(lo), [31:16]=bf16(hi)
  unsigned r;
  asm("v_cvt_pk_bf16_f32 %0, %1, %2" : "=v"(r) : "v"(lo), "v"(hi));
  return r;
}

DEVINL void gload_lds16(const void* g, void* l) {
  __builtin_amdgcn_global_load_lds((const __attribute__((address_space(1))) void*)g,
                                   (__attribute__((address_space(3))) void*)l,
                                   16, 0, 0);
}

#define SCALE 0.17677669529663687f
#define LOG2E 1.4426950408889634f

// ---------------- workspace layout (bytes) ----------------
#define WS_XB     ((size_t)0)            // 65536x448 bf16 (56MB), qkv only
#define WS_CTX    ((size_t)0)            // 65536x1024 bf16 (128MB), attn->proj
#define WS_WQT    ((size_t)134217728)    // 1536x448 bf16 (permuted, scaled)
#define WS_WPT    ((size_t)135593984)    // 512x1024 bf16 (rows 448..511 zero)
#define WS_QW     ((size_t)136642560)    // [2048][256][32] bf16 (scaled)
#define WS_KW     ((size_t)170196992)    // [2048][256][32] bf16
#define WS_VT     ((size_t)203751424)    // [2048][128][264] bf16
#define WS_QKVBP  ((size_t)342163456)    // 1536 f32 (permuted, scaled bias)

// column permutation: n' in [0,1536) -> n in original qkv order
DEVINL int qkv_perm(int np, float* sc) {
  *sc = 1.0f;
  if (np < 512) {
    const int h = np >> 6, c = np & 63;
    if (c < 32) *sc = SCALE * LOG2E;   // fold softmax scale + log2e into Q
    return h * 192 + c;
  }
  const int h = (np - 512) >> 7, e = (np - 512) & 127;
  return h * 192 + 64 + e;
}

// ---------------- prep kernels ----------------

__global__ void k_convert_x(const float* __restrict__ x, short* __restrict__ xb) {
  const size_t i = (size_t)blockIdx.x * blockDim.x + threadIdx.x;  // 8 elems each
  const f32x4* src = (const f32x4*)x + i * 2;
  f32x4 a = src[0], b = src[1];
  short8 o;
#pragma unroll
  for (int t = 0; t < 4; ++t) o[t] = (short)f2bf(a[t]);
#pragma unroll
  for (int t = 0; t < 4; ++t) o[4 + t] = (short)f2bf(b[t]);
  ((short8*)xb)[i] = o;
}

__global__ void k_prep_qkvw(const float* __restrict__ w, short* __restrict__ out) {
  const int idx = blockIdx.x * blockDim.x + threadIdx.x;  // [n'][k], 1536*448
  if (idx >= 1536 * 448) return;
  const int np = idx / 448, k = idx - np * 448;
  float sc;
  const int n = qkv_perm(np, &sc);
  out[idx] = (short)f2bf(w[(size_t)k * 1536 + n] * sc);
}

__global__ void k_prep_qkvb(const float* __restrict__ bsrc, float* __restrict__ bdst) {
  const int np = blockIdx.x * blockDim.x + threadIdx.x;
  if (np >= 1536) return;
  float sc;
  const int n = qkv_perm(np, &sc);
  bdst[np] = bsrc[n] * sc;
}

__global__ void k_transpose_bf16(const float* __restrict__ in, short* __restrict__ out,
                                 int K, int N, int total) {
  const int idx = blockIdx.x * blockDim.x + threadIdx.x;
  if (idx >= total) return;
  const int n = idx / K, k = idx - n * K;
  const float v = (n < N) ? in[(size_t)k * N + n] : 0.0f;
  out[idx] = (short)f2bf(v);
}

// ------- 128x128 GEMM mainloop: 3-deep counted-vmcnt pipeline (both GEMMs) -------
// A: 3 buffers (distance-2 prefetch covers HBM/L3-cold loads); B: 2 buffers.
// Issue order per step {B(k+1), A(k+2)} => steady s_waitcnt vmcnt(12) retires
// exactly {A(k),B(k)}; 12 loads stay in flight across raw s_barriers.
// sched_barrier(0) after each counted wait keeps stage-issue clustered ahead
// of compute (R14 A/B: removing it cost proj +6us). T2 XOR-swizzled LDS.

template <int KSTEPS, int LDA, int LDB, bool SWAP>
DEVINL void gemm128_pipe3(const short* __restrict__ A, const short* __restrict__ B,
                          short* Asm /*3*8192*/, short* Bsm /*2*8192*/,
                          int m0, int n0, int tid, f32x4 acc[4][4]) {
  const int lane = tid & 63, wave = tid >> 6;
  const int l15 = lane & 15, g = lane >> 4;
  const int wm = wave >> 1, wn = wave & 1;
  const int r8 = lane >> 3;
  const int scol = (((lane & 7) ^ r8) << 3);
  const int wbase = wave * 32;

  const short* Ab = A + (size_t)(m0 + wbase + r8) * LDA + scol;
  const short* Bb = B + (size_t)(n0 + wbase + r8) * LDB + scol;

  auto stageA = [&](int k) {
    short* dst = Asm + (k % 3) * 8192 + wbase * 64;
    const short* src = Ab + (size_t)k * 64;
#pragma unroll
    for (int c = 0; c < 4; ++c) gload_lds16(src + (size_t)(c * 8) * LDA, dst + c * 512);
  };
  auto stageB = [&](int k) {
    short* dst = Bsm + (k % 2) * 8192 + wbase * 64;
    const short* src = Bb + (size_t)k * 64;
#pragma unroll
    for (int c = 0; c < 4; ++c) gload_lds16(src + (size_t)(c * 8) * LDB, dst + c * 512);
  };
  auto compute = [&](int k) {
    const short* Ac = Asm + (k % 3) * 8192;
    const short* Bc = Bsm + (k % 2) * 8192;
#pragma unroll
    for (int s = 0; s < 2; ++s) {
      const int rslot = (((s * 4 + g) ^ (l15 & 7)) << 3);
      short8 a[4], b[4];
#pragma unroll
      for (int i = 0; i < 4; ++i)
        a[i] = *(const short8*)(Ac + (wm * 64 + i * 16 + l15) * 64 + rslot);
#pragma unroll
      for (int j = 0; j < 4; ++j)
        b[j] = *(const short8*)(Bc + (wn * 64 + j * 16 + l15) * 64 + rslot);
#pragma unroll
      for (int i = 0; i < 4; ++i)
#pragma unroll
        for (int j = 0; j < 4; ++j)
          acc[i][j] = SWAP
              ? __builtin_amdgcn_mfma_f32_16x16x32_bf16(b[j], a[i], acc[i][j], 0, 0, 0)
              : __builtin_amdgcn_mfma_f32_16x16x32_bf16(a[i], b[j], acc[i][j], 0, 0, 0);
    }
  };

  stageB(0); stageA(0); stageA(1);
  asm volatile("s_waitcnt vmcnt(4)" ::: "memory");
  __builtin_amdgcn_s_barrier();
  __builtin_amdgcn_sched_barrier(0);

#pragma unroll
  for (int ks = 0; ks < KSTEPS - 2; ++ks) {
    stageB(ks + 1);
    stageA(ks + 2);
    asm volatile("s_waitcnt vmcnt(12)" ::: "memory");
    __builtin_amdgcn_s_barrier();
    __builtin_amdgcn_sched_barrier(0);
    compute(ks);
    __builtin_amdgcn_s_barrier();
  }
  stageB(KSTEPS - 1);
  asm volatile("s_waitcnt vmcnt(8)" ::: "memory");
  __builtin_amdgcn_s_barrier();
  __builtin_amdgcn_sched_barrier(0);
  compute(KSTEPS - 2);
  __builtin_amdgcn_s_barrier();
  asm volatile("s_waitcnt vmcnt(0)" ::: "memory");
  __builtin_amdgcn_s_barrier();
  __builtin_amdgcn_sched_barrier(0);
  compute(KSTEPS - 1);
}

// ---------------- QKV GEMM: Xb[65536][448] @ W'^T -> Q/K/Vt ----------------

union QkvSmem {
  struct { short a[3 * 8192]; short b[2 * 8192]; } ab;   // 80 KB pipe3 buffers
  short tile[128 * 136];                                  // V epilogue transpose
};

__global__ __launch_bounds__(256) void k_qkv_gemm(
    const short* __restrict__ Xb, const short* __restrict__ Wt,
    const float* __restrict__ qkvbp,
    short* __restrict__ Qw, short* __restrict__ Kw, short* __restrict__ Vt) {
  __shared__ __align__(16) QkvSmem sm;
  const int tid = threadIdx.x;
  const int l = (blockIdx.x & 7) * 768 + (blockIdx.x >> 3);
  const int mt = l / 12, by = l - mt * 12;
  const int m0 = mt * 128, n0 = by * 128;

  const int lane = tid & 63, wave = tid >> 6;
  const int l15 = lane & 15, g = lane >> 4;
  const int wm = wave >> 1, wn = wave & 1;
  const int b0 = m0 >> 8, s0 = m0 & 255;

  f32x4 acc[4][4];
#pragma unroll
  for (int i = 0; i < 4; ++i)
#pragma unroll
    for (int j = 0; j < 4; ++j) acc[i][j] = (f32x4){0.f, 0.f, 0.f, 0.f};

  if (by >= 4) {
    gemm128_pipe3<7, 448, 448, false>(Xb, Wt, sm.ab.a, sm.ab.b, m0, n0, tid, acc);
    __syncthreads();   // pipe3 ends barrier-less; ab dead, tile goes live
#pragma unroll
    for (int i = 0; i < 4; ++i) {
#pragma unroll
      for (int j = 0; j < 4; ++j) {
        const float bv = qkvbp[n0 + wn * 64 + j * 16 + l15];
        u16x4 pk;
#pragma unroll
        for (int r = 0; r < 4; ++r) pk[r] = f2bf(acc[i][j][r] + bv);
        *(u16x4*)&sm.tile[(wn * 64 + j * 16 + l15) * 136 + wm * 64 + i * 16 + g * 4] = pk;
      }
    }
    __syncthreads();
    const int bh = b0 * 8 + (by - 4);
#pragma unroll
    for (int p = 0; p < 8; ++p) {
      const int er = p * 16 + (tid >> 4);
      const int sc = (tid & 15) * 8;
      short8 v = *(const short8*)&sm.tile[er * 136 + sc];
      *(short8*)(Vt + (size_t)bh * 33792 + er * 264 + s0 + sc) = v;
    }
  } else {
    gemm128_pipe3<7, 448, 448, true>(Xb, Wt, sm.ab.a, sm.ab.b, m0, n0, tid, acc);
#pragma unroll
    for (int i = 0; i < 4; ++i) {
      const int s = s0 + wm * 64 + i * 16 + l15;
#pragma unroll
      for (int j = 0; j < 4; ++j) {
        const int nbase = n0 + wn * 64 + j * 16 + g * 4;
        const f32x4 bv4 = *(const f32x4*)(qkvbp + nbase);
        u16x4 pk;
#pragma unroll
        for (int r = 0; r < 4; ++r) pk[r] = f2bf(acc[i][j][r] + bv4[r]);
        const int c = nbase & 63;
        const int bh = b0 * 8 + (by << 1) + (nbase >> 6 & 1);
        short* dst = (c < 32) ? (Qw + ((size_t)bh * 256 + s) * 32 + c)
                              : (Kw + ((size_t)bh * 256 + s) * 32 + (c - 32));
        *(u16x4*)dst = pk;
      }
    }
  }
}

// ---------------- fused attention per (b,h) ----------------
// R13 version: swapped-score exp2 no-max, cvt_pk bf16 stores, read-only
// row-sum, 2 barriers/phase, issue-early loads.

__global__ __launch_bounds__(512, 4) void k_attn(
    const short* __restrict__ Qw, const short* __restrict__ Kw,
    const short* __restrict__ Vt, const float* __restrict__ attb, int n_off,
    short* __restrict__ CTX) {
  __shared__ short Ps[4][32 * 264];
  __shared__ float rinv[2][4][32];
  __shared__ float bias_sm[256];

  const int tid = threadIdx.x, lane = tid & 63, wave = tid >> 6;  // 8 waves
  const int l15 = lane & 15, g = lane >> 4;
  const int bh = blockIdx.x;
  const int b = bh >> 3, h = bh & 7;

  if (tid < 256) bias_sm[tid] = attb[h * n_off + tid] * LOG2E;  // exp2 domain
  __syncthreads();

  int offc[4];
#pragma unroll
  for (int r = 0; r < 4; ++r) {
    const int d = g * 4 + r - l15;
    offc[r] = (d < 0) ? -d : d;
  }

  const short* Qb = Qw + (size_t)bh * 8192;
  const short* Kb = Kw + (size_t)bh * 8192;
  const short* Vb = Vt + (size_t)bh * 33792;
  const int e = wave * 16 + l15;

  for (int ph = 0; ph < 2; ++ph) {
    const int Q0 = ph * 128;

    // ---- issue all phase loads up-front (independent 16B each) ----
    short8 aq[4][2];
#pragma unroll
    for (int u = 0; u < 4; ++u)
#pragma unroll
      for (int i = 0; i < 2; ++i)
        aq[u][i] = *(const short8*)(Qb + (Q0 + u * 32 + i * 16 + l15) * 32 + g * 8);
    short8 bkk[2];
#pragma unroll
    for (int fj = 0; fj < 2; ++fj)
      bkk[fj] = *(const short8*)(Kb + (wave * 32 + fj * 16 + l15) * 32 + g * 8);
    short8 bvv[8];
#pragma unroll
    for (int ks = 0; ks < 8; ++ks)
      bvv[ks] = *(const short8*)(Vb + e * 264 + ks * 32 + g * 8);

    // ---- scores (swapped): wave covers keys [wave*32, +32). D[k][q]. ----
#pragma unroll
    for (int fj = 0; fj < 2; ++fj) {
      const int kk0 = wave * 32 + fj * 16;
      const int kr = wave * 2 + fj;
#pragma unroll
      for (int u = 0; u < 4; ++u) {
#pragma unroll
        for (int i = 0; i < 2; ++i) {
          const int qr = ph * 8 + u * 2 + i;
          const int ab = ((qr > kr) ? qr - kr : kr - qr) << 4;
          f32x4 acc;
#pragma unroll
          for (int r = 0; r < 4; ++r) acc[r] = bias_sm[ab + offc[r]];
          acc = __builtin_amdgcn_mfma_f32_16x16x32_bf16(bkk[fj], aq[u][i], acc, 0, 0, 0);
          u32x2 pk;
          pk.x = cvt_pk_bf16(exp2f(acc[0]), exp2f(acc[1]));
          pk.y = cvt_pk_bf16(exp2f(acc[2]), exp2f(acc[3]));
          *(u32x2*)&Ps[u][(i * 16 + l15) * 264 + kk0 + g * 4] = pk;
        }
      }
    }
    __syncthreads();  // B1: all P written

    // ---- row-sum (read-only): 512 threads = 32 rows x 16 parts ----
    {
      const int r = tid >> 4, part = tid & 15;
#pragma unroll
      for (int u = 0; u < 4; ++u) {
        const short* rowp = &Ps[u][r * 264 + part * 16];
        short8 x0 = ((const short8*)rowp)[0];
        short8 x1 = ((const short8*)rowp)[1];
        float sum = 0.f;
#pragma unroll
        for (int t = 0; t < 8; ++t) sum += bf2f(x0[t]) + bf2f(x1[t]);
#pragma unroll
        for (int d = 1; d < 16; d <<= 1) sum += __shfl_xor(sum, d);
        if (part == 0) rinv[ph][u][r] = 1.0f / sum;
      }
    }
    // no barrier: rinv only read after B2 below

    // ---- PV direct (A=P rows q, B=V^T cols e from REGISTERS) ----
    f32x4 cacc[4][2];
#pragma unroll
    for (int u = 0; u < 4; ++u)
#pragma unroll
      for (int qt = 0; qt < 2; ++qt) cacc[u][qt] = (f32x4){0.f, 0.f, 0.f, 0.f};

#pragma unroll
    for (int ks = 0; ks < 8; ++ks) {
#pragma unroll
      for (int u = 0; u < 4; ++u)
#pragma unroll
        for (int qt = 0; qt < 2; ++qt) {
          const short8 ap = *(const short8*)&Ps[u][(qt * 16 + l15) * 264 + ks * 32 + g * 8];
          cacc[u][qt] = __builtin_amdgcn_mfma_f32_16x16x32_bf16(ap, bvv[ks], cacc[u][qt], 0, 0, 0);
        }
    }
    __syncthreads();  // B2: Ps consumed (free for next phase), rinv visible

    // ---- epilogue: apply rinv, store ctx (cvt_pk pairs) ----
#pragma unroll
    for (int u = 0; u < 4; ++u)
#pragma unroll
      for (int qt = 0; qt < 2; ++qt) {
        const int qb = qt * 16 + g * 4;
        const size_t base = ((size_t)b * 256 + Q0 + u * 32 + qb) * 1024 + h * 128 + wave * 16 + l15;
#pragma unroll
        for (int r = 0; r < 4; r += 2) {
          const unsigned pw = cvt_pk_bf16(cacc[u][qt][r] * rinv[ph][u][qb + r],
                                          cacc[u][qt][r + 1] * rinv[ph][u][qb + r + 1]);
          CTX[base + (size_t)r * 1024] = (short)(pw & 0xffffu);
          CTX[base + (size_t)(r + 1) * 1024] = (short)(pw >> 16);
        }
      }
  }
}

// ---------------- proj GEMM: CTX[65536][1024] @ WPT -> out f32 ----------------

__global__ __launch_bounds__(256) void k_proj_gemm(
    const short* __restrict__ CTX, const short* __restrict__ Wpt,
    const float* __restrict__ projb, float* __restrict__ out) {
  __shared__ __align__(16) short Asm[3 * 8192];
  __shared__ __align__(16) short Bsm[2 * 8192];
  const int tid = threadIdx.x;
  const int l = (blockIdx.x & 7) * 256 + (blockIdx.x >> 3);
  const int mt = l >> 2, nt = l & 3;
  const int m0 = mt * 128, n0 = nt * 128;
  f32x4 acc[4][4];
#pragma unroll
  for (int i = 0; i < 4; ++i)
#pragma unroll
    for (int j = 0; j < 4; ++j) acc[i][j] = (f32x4){0.f, 0.f, 0.f, 0.f};

  gemm128_pipe3<16, 1024, 1024, false>(CTX, Wpt, Asm, Bsm, m0, n0, tid, acc);

  const int lane = tid & 63, wave = tid >> 6;
  const int l15 = lane & 15, g = lane >> 4;
  const int wm = wave >> 1, wn = wave & 1;
#pragma unroll
  for (int i = 0; i < 4; ++i) {
    const int mb = m0 + wm * 64 + i * 16 + g * 4;
#pragma unroll
    for (int j = 0; j < 4; ++j) {
      const int n = n0 + wn * 64 + j * 16 + l15;
      if (n < 448) {
        const float bv = projb[n];
#pragma unroll
        for (int r = 0; r < 4; ++r)
          out[(size_t)(mb + r) * 448 + n] = acc[i][j][r] + bv;
      }
    }
  }
}

// ---------------- launch ----------------

extern "C" void kernel_launch(void* const* d_in, const int* in_sizes, int n_in,
                              void* d_out, int out_size, void* d_ws, size_t ws_size,
                              hipStream_t stream) {
  const float* X      = (const float*)d_in[0];
  const float* qkv_w  = (const float*)d_in[1];
  const float* qkv_b  = (const float*)d_in[2];
  const float* proj_w = (const float*)d_in[3];
  const float* proj_b = (const float*)d_in[4];
  const float* att_b  = (const float*)d_in[5];
  const int n_off = in_sizes[5] / 8;

  char* ws = (char*)d_ws;
  short* Xb    = (short*)(ws + WS_XB);
  short* CTX   = (short*)(ws + WS_CTX);
  short* WQT   = (short*)(ws + WS_WQT);
  short* WPT   = (short*)(ws + WS_WPT);
  short* Qw    = (short*)(ws + WS_QW);
  short* Kw    = (short*)(ws + WS_KW);
  short* Vt    = (short*)(ws + WS_VT);
  float* QKVBP = (float*)(ws + WS_QKVBP);

  k_convert_x<<<14336, 256, 0, stream>>>(X, Xb);
  k_prep_qkvw<<<(1536 * 448 + 255) / 256, 256, 0, stream>>>(qkv_w, WQT);
  k_prep_qkvb<<<6, 256, 0, stream>>>(qkv_b, QKVBP);
  k_transpose_bf16<<<(512 * 1024 + 255) / 256, 256, 0, stream>>>(proj_w, WPT, 1024, 448, 512 * 1024);

  k_qkv_gemm<<<6144, 256, 0, stream>>>(Xb, WQT, QKVBP, Qw, Kw, Vt);
  k_attn<<<2048, 512, 0, stream>>>(Qw, Kw, Vt, att_b, n_off, CTX);
  k_proj_gemm<<<2048, 256, 0, stream>>>(CTX, WPT, proj_b, (float*)d_out);
}

// Round 17
// 334.910 us; speedup vs baseline: 1.0973x; 1.0750x over previous
//
#include <hip/hip_runtime.h>
#include <hip/hip_bf16.h>
#include <stdint.h>

// ---------------------------------------------------------------------------
// TFEfficientFormerSelfAttention  (B=256, S=256, DIM=448, H=8, KD=32, EKD=128)
// Round 17: R16's 4-phase 256x256 proj + the race fix — sched_barrier(0)
// after EVERY stage call. R16's counted-vmcnt watermarks assumed program-
// order issue of global_load_lds; stages sharing an asm-free window
// (prologue x4; p3-stage with next p0-stage) could be permuted by the
// machine scheduler, breaking the "oldest N landed" accounting -> stale LDS
// reads (first-call absmax 7.3e-4, replay 2.6e-3). Pinning each stage closes
// every window. qkv (pipe3) and attn (R13) untouched.
// MFMA fragment layouts (verified m89/m91):
//   A: row=l&15, k=(l>>4)*8+j ; B: col=l&15, k=(l>>4)*8+j ;
//   D: col=l&15, row=(l>>4)*4+r.
// ---------------------------------------------------------------------------

typedef __attribute__((ext_vector_type(4))) float f32x4;
typedef __attribute__((ext_vector_type(8))) short short8;
typedef __attribute__((ext_vector_type(4))) unsigned short u16x4;
typedef __attribute__((ext_vector_type(2))) unsigned int u32x2;

#define DEVINL static __device__ __forceinline__

DEVINL unsigned short f2bf(float f) {
  unsigned u = __float_as_uint(f);
  return (unsigned short)((u + 0x7FFFu + ((u >> 16) & 1u)) >> 16);
}
DEVINL float bf2f(short s) {
  return __uint_as_float(((unsigned)(unsigned short)s) << 16);
}
DEVINL unsigned cvt_pk_bf16(float lo, float hi) {
  unsigned r;
  asm("v_cvt_pk_bf16_f32 %0, %1, %2" : "=v"(r) : "v"(lo), "v"(hi));
  return r;
}

DEVINL void gload_lds16(const void* g, void* l) {
  __builtin_amdgcn_global_load_lds((const __attribute__((address_space(1))) void*)g,
                                   (__attribute__((address_space(3))) void*)l,
                                   16, 0, 0);
}

#define SCALE 0.17677669529663687f
#define LOG2E 1.4426950408889634f

// ---------------- workspace layout (bytes) ----------------
#define WS_XB     ((size_t)0)
#define WS_CTX    ((size_t)0)
#define WS_WQT    ((size_t)134217728)
#define WS_WPT    ((size_t)135593984)
#define WS_QW     ((size_t)136642560)
#define WS_KW     ((size_t)170196992)
#define WS_VT     ((size_t)203751424)
#define WS_QKVBP  ((size_t)342163456)

DEVINL int qkv_perm(int np, float* sc) {
  *sc = 1.0f;
  if (np < 512) {
    const int h = np >> 6, c = np & 63;
    if (c < 32) *sc = SCALE * LOG2E;
    return h * 192 + c;
  }
  const int h = (np - 512) >> 7, e = (np - 512) & 127;
  return h * 192 + 64 + e;
}

// ---------------- prep kernels ----------------

__global__ void k_convert_x(const float* __restrict__ x, short* __restrict__ xb) {
  const size_t i = (size_t)blockIdx.x * blockDim.x + threadIdx.x;
  const f32x4* src = (const f32x4*)x + i * 2;
  f32x4 a = src[0], b = src[1];
  short8 o;
#pragma unroll
  for (int t = 0; t < 4; ++t) o[t] = (short)f2bf(a[t]);
#pragma unroll
  for (int t = 0; t < 4; ++t) o[4 + t] = (short)f2bf(b[t]);
  ((short8*)xb)[i] = o;
}

__global__ void k_prep_qkvw(const float* __restrict__ w, short* __restrict__ out) {
  const int idx = blockIdx.x * blockDim.x + threadIdx.x;
  if (idx >= 1536 * 448) return;
  const int np = idx / 448, k = idx - np * 448;
  float sc;
  const int n = qkv_perm(np, &sc);
  out[idx] = (short)f2bf(w[(size_t)k * 1536 + n] * sc);
}

__global__ void k_prep_qkvb(const float* __restrict__ bsrc, float* __restrict__ bdst) {
  const int np = blockIdx.x * blockDim.x + threadIdx.x;
  if (np >= 1536) return;
  float sc;
  const int n = qkv_perm(np, &sc);
  bdst[np] = bsrc[n] * sc;
}

__global__ void k_transpose_bf16(const float* __restrict__ in, short* __restrict__ out,
                                 int K, int N, int total) {
  const int idx = blockIdx.x * blockDim.x + threadIdx.x;
  if (idx >= total) return;
  const int n = idx / K, k = idx - n * K;
  const float v = (n < N) ? in[(size_t)k * N + n] : 0.0f;
  out[idx] = (short)f2bf(v);
}

// ------- 128x128 GEMM mainloop: 3-deep counted-vmcnt pipeline (qkv) -------

template <int KSTEPS, int LDA, int LDB, bool SWAP>
DEVINL void gemm128_pipe3(const short* __restrict__ A, const short* __restrict__ B,
                          short* Asm /*3*8192*/, short* Bsm /*2*8192*/,
                          int m0, int n0, int tid, f32x4 acc[4][4]) {
  const int lane = tid & 63, wave = tid >> 6;
  const int l15 = lane & 15, g = lane >> 4;
  const int wm = wave >> 1, wn = wave & 1;
  const int r8 = lane >> 3;
  const int scol = (((lane & 7) ^ r8) << 3);
  const int wbase = wave * 32;

  const short* Ab = A + (size_t)(m0 + wbase + r8) * LDA + scol;
  const short* Bb = B + (size_t)(n0 + wbase + r8) * LDB + scol;

  auto stageA = [&](int k) {
    short* dst = Asm + (k % 3) * 8192 + wbase * 64;
    const short* src = Ab + (size_t)k * 64;
#pragma unroll
    for (int c = 0; c < 4; ++c) gload_lds16(src + (size_t)(c * 8) * LDA, dst + c * 512);
    __builtin_amdgcn_sched_barrier(0);
  };
  auto stageB = [&](int k) {
    short* dst = Bsm + (k % 2) * 8192 + wbase * 64;
    const short* src = Bb + (size_t)k * 64;
#pragma unroll
    for (int c = 0; c < 4; ++c) gload_lds16(src + (size_t)(c * 8) * LDB, dst + c * 512);
    __builtin_amdgcn_sched_barrier(0);
  };
  auto compute = [&](int k) {
    const short* Ac = Asm + (k % 3) * 8192;
    const short* Bc = Bsm + (k % 2) * 8192;
#pragma unroll
    for (int s = 0; s < 2; ++s) {
      const int rslot = (((s * 4 + g) ^ (l15 & 7)) << 3);
      short8 a[4], b[4];
#pragma unroll
      for (int i = 0; i < 4; ++i)
        a[i] = *(const short8*)(Ac + (wm * 64 + i * 16 + l15) * 64 + rslot);
#pragma unroll
      for (int j = 0; j < 4; ++j)
        b[j] = *(const short8*)(Bc + (wn * 64 + j * 16 + l15) * 64 + rslot);
#pragma unroll
      for (int i = 0; i < 4; ++i)
#pragma unroll
        for (int j = 0; j < 4; ++j)
          acc[i][j] = SWAP
              ? __builtin_amdgcn_mfma_f32_16x16x32_bf16(b[j], a[i], acc[i][j], 0, 0, 0)
              : __builtin_amdgcn_mfma_f32_16x16x32_bf16(a[i], b[j], acc[i][j], 0, 0, 0);
    }
  };

  stageB(0); stageA(0); stageA(1);
  asm volatile("s_waitcnt vmcnt(4)" ::: "memory");
  __builtin_amdgcn_s_barrier();
  __builtin_amdgcn_sched_barrier(0);

#pragma unroll
  for (int ks = 0; ks < KSTEPS - 2; ++ks) {
    stageB(ks + 1);
    stageA(ks + 2);
    asm volatile("s_waitcnt vmcnt(12)" ::: "memory");
    __builtin_amdgcn_s_barrier();
    __builtin_amdgcn_sched_barrier(0);
    compute(ks);
    __builtin_amdgcn_s_barrier();
  }
  stageB(KSTEPS - 1);
  asm volatile("s_waitcnt vmcnt(8)" ::: "memory");
  __builtin_amdgcn_s_barrier();
  __builtin_amdgcn_sched_barrier(0);
  compute(KSTEPS - 2);
  __builtin_amdgcn_s_barrier();
  asm volatile("s_waitcnt vmcnt(0)" ::: "memory");
  __builtin_amdgcn_s_barrier();
  __builtin_amdgcn_sched_barrier(0);
  compute(KSTEPS - 1);
}

// ---------------- QKV GEMM: Xb[65536][448] @ W'^T -> Q/K/Vt ----------------

union QkvSmem {
  struct { short a[3 * 8192]; short b[2 * 8192]; } ab;
  short tile[128 * 136];
};

__global__ __launch_bounds__(256) void k_qkv_gemm(
    const short* __restrict__ Xb, const short* __restrict__ Wt,
    const float* __restrict__ qkvbp,
    short* __restrict__ Qw, short* __restrict__ Kw, short* __restrict__ Vt) {
  __shared__ __align__(16) QkvSmem sm;
  const int tid = threadIdx.x;
  const int l = (blockIdx.x & 7) * 768 + (blockIdx.x >> 3);
  const int mt = l / 12, by = l - mt * 12;
  const int m0 = mt * 128, n0 = by * 128;

  const int lane = tid & 63, wave = tid >> 6;
  const int l15 = lane & 15, g = lane >> 4;
  const int wm = wave >> 1, wn = wave & 1;
  const int b0 = m0 >> 8, s0 = m0 & 255;

  f32x4 acc[4][4];
#pragma unroll
  for (int i = 0; i < 4; ++i)
#pragma unroll
    for (int j = 0; j < 4; ++j) acc[i][j] = (f32x4){0.f, 0.f, 0.f, 0.f};

  if (by >= 4) {
    gemm128_pipe3<7, 448, 448, false>(Xb, Wt, sm.ab.a, sm.ab.b, m0, n0, tid, acc);
    __syncthreads();
#pragma unroll
    for (int i = 0; i < 4; ++i) {
#pragma unroll
      for (int j = 0; j < 4; ++j) {
        const float bv = qkvbp[n0 + wn * 64 + j * 16 + l15];
        u16x4 pk;
#pragma unroll
        for (int r = 0; r < 4; ++r) pk[r] = f2bf(acc[i][j][r] + bv);
        *(u16x4*)&sm.tile[(wn * 64 + j * 16 + l15) * 136 + wm * 64 + i * 16 + g * 4] = pk;
      }
    }
    __syncthreads();
    const int bh = b0 * 8 + (by - 4);
#pragma unroll
    for (int p = 0; p < 8; ++p) {
      const int er = p * 16 + (tid >> 4);
      const int sc = (tid & 15) * 8;
      short8 v = *(const short8*)&sm.tile[er * 136 + sc];
      *(short8*)(Vt + (size_t)bh * 33792 + er * 264 + s0 + sc) = v;
    }
  } else {
    gemm128_pipe3<7, 448, 448, true>(Xb, Wt, sm.ab.a, sm.ab.b, m0, n0, tid, acc);
#pragma unroll
    for (int i = 0; i < 4; ++i) {
      const int s = s0 + wm * 64 + i * 16 + l15;
#pragma unroll
      for (int j = 0; j < 4; ++j) {
        const int nbase = n0 + wn * 64 + j * 16 + g * 4;
        const f32x4 bv4 = *(const f32x4*)(qkvbp + nbase);
        u16x4 pk;
#pragma unroll
        for (int r = 0; r < 4; ++r) pk[r] = f2bf(acc[i][j][r] + bv4[r]);
        const int c = nbase & 63;
        const int bh = b0 * 8 + (by << 1) + (nbase >> 6 & 1);
        short* dst = (c < 32) ? (Qw + ((size_t)bh * 256 + s) * 32 + c)
                              : (Kw + ((size_t)bh * 256 + s) * 32 + (c - 32));
        *(u16x4*)dst = pk;
      }
    }
  }
}

// ---------------- fused attention per (b,h) (R13) ----------------

__global__ __launch_bounds__(512, 4) void k_attn(
    const short* __restrict__ Qw, const short* __restrict__ Kw,
    const short* __restrict__ Vt, const float* __restrict__ attb, int n_off,
    short* __restrict__ CTX) {
  __shared__ short Ps[4][32 * 264];
  __shared__ float rinv[2][4][32];
  __shared__ float bias_sm[256];

  const int tid = threadIdx.x, lane = tid & 63, wave = tid >> 6;
  const int l15 = lane & 15, g = lane >> 4;
  const int bh = blockIdx.x;
  const int b = bh >> 3, h = bh & 7;

  if (tid < 256) bias_sm[tid] = attb[h * n_off + tid] * LOG2E;
  __syncthreads();

  int offc[4];
#pragma unroll
  for (int r = 0; r < 4; ++r) {
    const int d = g * 4 + r - l15;
    offc[r] = (d < 0) ? -d : d;
  }

  const short* Qb = Qw + (size_t)bh * 8192;
  const short* Kb = Kw + (size_t)bh * 8192;
  const short* Vb = Vt + (size_t)bh * 33792;
  const int e = wave * 16 + l15;

  for (int ph = 0; ph < 2; ++ph) {
    const int Q0 = ph * 128;

    short8 aq[4][2];
#pragma unroll
    for (int u = 0; u < 4; ++u)
#pragma unroll
      for (int i = 0; i < 2; ++i)
        aq[u][i] = *(const short8*)(Qb + (Q0 + u * 32 + i * 16 + l15) * 32 + g * 8);
    short8 bkk[2];
#pragma unroll
    for (int fj = 0; fj < 2; ++fj)
      bkk[fj] = *(const short8*)(Kb + (wave * 32 + fj * 16 + l15) * 32 + g * 8);
    short8 bvv[8];
#pragma unroll
    for (int ks = 0; ks < 8; ++ks)
      bvv[ks] = *(const short8*)(Vb + e * 264 + ks * 32 + g * 8);

#pragma unroll
    for (int fj = 0; fj < 2; ++fj) {
      const int kk0 = wave * 32 + fj * 16;
      const int kr = wave * 2 + fj;
#pragma unroll
      for (int u = 0; u < 4; ++u) {
#pragma unroll
        for (int i = 0; i < 2; ++i) {
          const int qr = ph * 8 + u * 2 + i;
          const int ab = ((qr > kr) ? qr - kr : kr - qr) << 4;
          f32x4 acc;
#pragma unroll
          for (int r = 0; r < 4; ++r) acc[r] = bias_sm[ab + offc[r]];
          acc = __builtin_amdgcn_mfma_f32_16x16x32_bf16(bkk[fj], aq[u][i], acc, 0, 0, 0);
          u32x2 pk;
          pk.x = cvt_pk_bf16(exp2f(acc[0]), exp2f(acc[1]));
          pk.y = cvt_pk_bf16(exp2f(acc[2]), exp2f(acc[3]));
          *(u32x2*)&Ps[u][(i * 16 + l15) * 264 + kk0 + g * 4] = pk;
        }
      }
    }
    __syncthreads();  // B1

    {
      const int r = tid >> 4, part = tid & 15;
#pragma unroll
      for (int u = 0; u < 4; ++u) {
        const short* rowp = &Ps[u][r * 264 + part * 16];
        short8 x0 = ((const short8*)rowp)[0];
        short8 x1 = ((const short8*)rowp)[1];
        float sum = 0.f;
#pragma unroll
        for (int t = 0; t < 8; ++t) sum += bf2f(x0[t]) + bf2f(x1[t]);
#pragma unroll
        for (int d = 1; d < 16; d <<= 1) sum += __shfl_xor(sum, d);
        if (part == 0) rinv[ph][u][r] = 1.0f / sum;
      }
    }

    f32x4 cacc[4][2];
#pragma unroll
    for (int u = 0; u < 4; ++u)
#pragma unroll
      for (int qt = 0; qt < 2; ++qt) cacc[u][qt] = (f32x4){0.f, 0.f, 0.f, 0.f};

#pragma unroll
    for (int ks = 0; ks < 8; ++ks) {
#pragma unroll
      for (int u = 0; u < 4; ++u)
#pragma unroll
        for (int qt = 0; qt < 2; ++qt) {
          const short8 ap = *(const short8*)&Ps[u][(qt * 16 + l15) * 264 + ks * 32 + g * 8];
          cacc[u][qt] = __builtin_amdgcn_mfma_f32_16x16x32_bf16(ap, bvv[ks], cacc[u][qt], 0, 0, 0);
        }
    }
    __syncthreads();  // B2

#pragma unroll
    for (int u = 0; u < 4; ++u)
#pragma unroll
      for (int qt = 0; qt < 2; ++qt) {
        const int qb = qt * 16 + g * 4;
        const size_t base = ((size_t)b * 256 + Q0 + u * 32 + qb) * 1024 + h * 128 + wave * 16 + l15;
#pragma unroll
        for (int r = 0; r < 4; r += 2) {
          const unsigned pw = cvt_pk_bf16(cacc[u][qt][r] * rinv[ph][u][qb + r],
                                          cacc[u][qt][r + 1] * rinv[ph][u][qb + r + 1]);
          CTX[base + (size_t)r * 1024] = (short)(pw & 0xffffu);
          CTX[base + (size_t)(r + 1) * 1024] = (short)(pw >> 16);
        }
      }
  }
}

// -------- proj GEMM: 256x256 tile, 8 waves, 4-phase counted-vmcnt --------
// Every stage call is followed by sched_barrier(0): the vmcnt watermark math
// requires program-order issue of the gload_lds intrinsics (R16 race fix).

__global__ __launch_bounds__(512, 2) void k_proj_gemm(
    const short* __restrict__ CTX, const short* __restrict__ Wpt,
    const float* __restrict__ projb, float* __restrict__ out) {
  __shared__ __align__(16) short Ab[2][2 * 8192];
  __shared__ __align__(16) short Bb[2][2 * 8192];

  const int tid = threadIdx.x, lane = tid & 63, wave = tid >> 6;  // 8 waves
  const int l15 = lane & 15, g = lane >> 4;
  const int l = (blockIdx.x & 7) * 64 + (blockIdx.x >> 3);
  const int mt = l >> 1, nt = l & 1;
  const int m0 = mt * 256, n0 = nt * 256;

  const int fmB = (wave & 3) * 2;
  const int fnB = (wave >> 2) * 4;

  const int r8 = lane >> 3;
  const int scol = (((lane & 7) ^ r8) << 3);

  const short* Asrc = CTX + (size_t)m0 * 1024 + scol;
  const short* Bsrc = Wpt + (size_t)n0 * 1024 + scol;

  auto stageA = [&](int kt, int half) {
    short* dst = &Ab[kt & 1][half * 8192];
#pragma unroll
    for (int c = 0; c < 2; ++c) {
      const int row0 = c * 64 + wave * 8;
      gload_lds16(Asrc + (size_t)(half * 128 + row0 + r8) * 1024 + kt * 64,
                  dst + row0 * 64);
    }
    __builtin_amdgcn_sched_barrier(0);
  };
  auto stageB = [&](int kt, int half) {
    short* dst = &Bb[kt & 1][half * 8192];
#pragma unroll
    for (int c = 0; c < 2; ++c) {
      const int row0 = c * 64 + wave * 8;
      gload_lds16(Bsrc + (size_t)(half * 128 + row0 + r8) * 1024 + kt * 64,
                  dst + row0 * 64);
    }
    __builtin_amdgcn_sched_barrier(0);
  };

  f32x4 acc[2][2][2][4];
#pragma unroll
  for (int a = 0; a < 2; ++a)
#pragma unroll
    for (int bq = 0; bq < 2; ++bq)
#pragma unroll
      for (int i = 0; i < 2; ++i)
#pragma unroll
        for (int j = 0; j < 4; ++j) acc[a][bq][i][j] = (f32x4){0.f, 0.f, 0.f, 0.f};

  short8 Ar[2][2][2];
  short8 Br[4][2];

  auto readA = [&](int par, int hm) {
    const short* base = &Ab[par][hm * 8192];
#pragma unroll
    for (int fi = 0; fi < 2; ++fi)
#pragma unroll
      for (int ks = 0; ks < 2; ++ks)
        Ar[hm][fi][ks] = *(const short8*)(base + ((fmB + fi) * 16 + l15) * 64 +
                                          (((ks * 4 + g) ^ (l15 & 7)) << 3));
  };
  auto readB = [&](int par, int hn) {
    const short* base = &Bb[par][hn * 8192];
#pragma unroll
    for (int fi = 0; fi < 4; ++fi)
#pragma unroll
      for (int ks = 0; ks < 2; ++ks)
        Br[fi][ks] = *(const short8*)(base + ((fnB + fi) * 16 + l15) * 64 +
                                      (((ks * 4 + g) ^ (l15 & 7)) << 3));
  };
  auto mfmaQ = [&](int hm, int hn) {
#pragma unroll
    for (int ks = 0; ks < 2; ++ks)
#pragma unroll
      for (int fi = 0; fi < 2; ++fi)
#pragma unroll
        for (int fj = 0; fj < 4; ++fj)
          acc[hm][hn][fi][fj] = __builtin_amdgcn_mfma_f32_16x16x32_bf16(
              Ar[hm][fi][ks], Br[fj][ks], acc[hm][hn][fi][fj], 0, 0, 0);
  };

  // prologue: tile 0 halves, pinned order A0,B0,A1,B1
  stageA(0, 0); stageB(0, 0); stageA(0, 1); stageB(0, 1);

  for (int T = 0; T < 15; ++T) {
    const int par = T & 1;
    // p0: Q00
    stageA(T + 1, 0);
    asm volatile("s_waitcnt vmcnt(6)" ::: "memory");
    __builtin_amdgcn_s_barrier();
    __builtin_amdgcn_sched_barrier(0);
    readA(par, 0); readB(par, 0);
    mfmaQ(0, 0);
    // p1: Q10
    stageB(T + 1, 0);
    asm volatile("s_waitcnt vmcnt(6)" ::: "memory");
    __builtin_amdgcn_s_barrier();
    __builtin_amdgcn_sched_barrier(0);
    readA(par, 1);
    mfmaQ(1, 0);
    // p2: Q11
    stageA(T + 1, 1);
    asm volatile("s_waitcnt vmcnt(6)" ::: "memory");
    __builtin_amdgcn_s_barrier();
    __builtin_amdgcn_sched_barrier(0);
    readB(par, 1);
    mfmaQ(1, 1);
    // p3: Q01 (pure register compute; stage B1 rides under it)
    stageB(T + 1, 1);
    mfmaQ(0, 1);
  }
  // T = 15 (drain)
  {
    asm volatile("s_waitcnt vmcnt(4)" ::: "memory");
    __builtin_amdgcn_s_barrier();
    __builtin_amdgcn_sched_barrier(0);
    readA(1, 0); readB(1, 0);
    mfmaQ(0, 0);
    asm volatile("s_waitcnt vmcnt(2)" ::: "memory");
    __builtin_amdgcn_s_barrier();
    __builtin_amdgcn_sched_barrier(0);
    readA(1, 1);
    mfmaQ(1, 0);
    asm volatile("s_waitcnt vmcnt(0)" ::: "memory");
    __builtin_amdgcn_s_barrier();
    __builtin_amdgcn_sched_barrier(0);
    readB(1, 1);
    mfmaQ(1, 1);
    mfmaQ(0, 1);
  }

#pragma unroll
  for (int hm = 0; hm < 2; ++hm)
#pragma unroll
    for (int hn = 0; hn < 2; ++hn)
#pragma unroll
      for (int fi = 0; fi < 2; ++fi)
#pragma unroll
        for (int fj = 0; fj < 4; ++fj) {
          const int n = n0 + hn * 128 + (fnB + fj) * 16 + l15;
          if (n < 448) {
            const float bv = projb[n];
            const int mb = m0 + hm * 128 + (fmB + fi) * 16 + g * 4;
#pragma unroll
            for (int r = 0; r < 4; ++r)
              out[(size_t)(mb + r) * 448 + n] = acc[hm][hn][fi][fj][r] + bv;
          }
        }
}

// ---------------- launch ----------------

extern "C" void kernel_launch(void* const* d_in, const int* in_sizes, int n_in,
                              void* d_out, int out_size, void* d_ws, size_t ws_size,
                              hipStream_t stream) {
  const float* X      = (const float*)d_in[0];
  const float* qkv_w  = (const float*)d_in[1];
  const float* qkv_b  = (const float*)d_in[2];
  const float* proj_w = (const float*)d_in[3];
  const float* proj_b = (const float*)d_in[4];
  const float* att_b  = (const float*)d_in[5];
  const int n_off = in_sizes[5] / 8;

  char* ws = (char*)d_ws;
  short* Xb    = (short*)(ws + WS_XB);
  short* CTX   = (short*)(ws + WS_CTX);
  short* WQT   = (short*)(ws + WS_WQT);
  short* WPT   = (short*)(ws + WS_WPT);
  short* Qw    = (short*)(ws + WS_QW);
  short* Kw    = (short*)(ws + WS_KW);
  short* Vt    = (short*)(ws + WS_VT);
  float* QKVBP = (float*)(ws + WS_QKVBP);

  k_convert_x<<<14336, 256, 0, stream>>>(X, Xb);
  k_prep_qkvw<<<(1536 * 448 + 255) / 256, 256, 0, stream>>>(qkv_w, WQT);
  k_prep_qkvb<<<6, 256, 0, stream>>>(qkv_b, QKVBP);
  k_transpose_bf16<<<(512 * 1024 + 255) / 256, 256, 0, stream>>>(proj_w, WPT, 1024, 448, 512 * 1024);

  k_qkv_gemm<<<6144, 256, 0, stream>>>(Xb, WQT, QKVBP, Qw, Kw, Vt);
  k_attn<<<2048, 512, 0, stream>>>(Qw, Kw, Vt, att_b, n_off, CTX);
  k_proj_gemm<<<512, 512, 0, stream>>>(CTX, WPT, proj_b, (float*)d_out);
}